// Round 1
// baseline (1142.439 us; speedup 1.0000x reference)
//
#include <hip/hip_runtime.h>

// Problem constants (fixed by reference):
#define B_ROWS   131072
#define DIM      1024
#define NH       21
// Tiling:
#define TILE_ROWS 128
#define BK        64
#define BKP       68              // padded x row stride (floats): 68 mod 32 = 4 -> conflict-free b128
#define NWAVES    3
#define HPW       7               // heads per wave (3*7 = 21)
#define BLOCK     (NWAVES * 64)   // 192 threads

__global__ __launch_bounds__(BLOCK) void linmodel_kernel(
    const float* __restrict__ x,      // [B, DIM]
    const float* __restrict__ vconf,  // [B, NH]
    const float* __restrict__ W,      // [NH, DIM]
    const float* __restrict__ bias,   // [NH]
    float* __restrict__ result,       // [B]
    float* __restrict__ out)          // [B, NH]
{
    // xs: [TILE_ROWS][BKP], ws: [NH][BK], psum overlays xs after the K loop.
    __shared__ float smem[TILE_ROWS * BKP + NH * BK];
    float* xs = smem;
    float* ws = smem + TILE_ROWS * BKP;
    float* psum = smem;  // [NWAVES][TILE_ROWS] overlay

    const int tid  = threadIdx.x;
    const int wave = tid >> 6;
    const int lane = tid & 63;
    const int base = blockIdx.x * TILE_ROWS;
    const int h0   = wave * HPW;

    float acc[2][HPW];
#pragma unroll
    for (int j = 0; j < 2; ++j)
#pragma unroll
        for (int i = 0; i < HPW; ++i) acc[j][i] = 0.f;

    for (int k0 = 0; k0 < DIM; k0 += BK) {
        __syncthreads();  // previous chunk's compute done before LDS overwrite
        // Stage x tile: 128 rows x 64 cols = 2048 float4, coalesced (16 lanes per row).
#pragma unroll 1
        for (int l = tid; l < TILE_ROWS * (BK / 4); l += BLOCK) {
            const int row = l >> 4;
            const int c4  = l & 15;
            float4 v = *(const float4*)(x + (size_t)(base + row) * DIM + k0 + c4 * 4);
            *(float4*)(xs + row * BKP + c4 * 4) = v;
        }
        // Stage W chunk: 21 x 16 = 336 float4.
#pragma unroll 1
        for (int l = tid; l < NH * (BK / 4); l += BLOCK) {
            const int h  = l >> 4;
            const int c4 = l & 15;
            float4 v = *(const float4*)(W + (size_t)h * DIM + k0 + c4 * 4);
            *(float4*)(ws + h * BK + c4 * 4) = v;
        }
        __syncthreads();

        // Compute: per float4 column group: 2 x-reads + 7 broadcast W-reads -> 56 FMAs.
#pragma unroll
        for (int c4 = 0; c4 < BK / 4; ++c4) {
            const float4 x0 = *(const float4*)(xs + lane * BKP + c4 * 4);
            const float4 x1 = *(const float4*)(xs + (lane + 64) * BKP + c4 * 4);
#pragma unroll
            for (int i = 0; i < HPW; ++i) {
                const float4 w = *(const float4*)(ws + (h0 + i) * BK + c4 * 4);
                acc[0][i] += x0.x * w.x + x0.y * w.y + x0.z * w.z + x0.w * w.w;
                acc[1][i] += x1.x * w.x + x1.y * w.y + x1.z * w.z + x1.w * w.w;
            }
        }
    }
    __syncthreads();  // xs dead; safe to overlay psum

    float bv[HPW];
#pragma unroll
    for (int i = 0; i < HPW; ++i) bv[i] = bias[h0 + i];

#pragma unroll
    for (int j = 0; j < 2; ++j) {
        const int rl = lane + 64 * j;
        const size_t grow = (size_t)(base + rl);
        float partial = 0.f;
#pragma unroll
        for (int i = 0; i < HPW; ++i) {
            const float o = acc[j][i] + bv[i];
            out[grow * NH + h0 + i] = o;
            partial += o * vconf[grow * NH + h0 + i];
        }
        psum[wave * TILE_ROWS + rl] = partial;
    }
    __syncthreads();

    if (tid < TILE_ROWS) {
        const float r = psum[tid] + psum[TILE_ROWS + tid] + psum[2 * TILE_ROWS + tid];
        result[base + tid] = r;
    }
}

extern "C" void kernel_launch(void* const* d_in, const int* in_sizes, int n_in,
                              void* d_out, int out_size, void* d_ws, size_t ws_size,
                              hipStream_t stream) {
    const float* x     = (const float*)d_in[0];
    const float* vconf = (const float*)d_in[1];
    const float* W     = (const float*)d_in[2];
    const float* bias  = (const float*)d_in[3];
    // d_out = [result (B floats) | out (B*NH floats)]
    float* result = (float*)d_out;
    float* out    = (float*)d_out + B_ROWS;

    const int nblocks = B_ROWS / TILE_ROWS;  // 1024
    linmodel_kernel<<<dim3(nblocks), dim3(BLOCK), 0, stream>>>(
        x, vconf, W, bias, result, out);
}

// Round 2
// 1039.315 us; speedup vs baseline: 1.0992x; 1.0992x over previous
//
#include <hip/hip_runtime.h>

// Problem: out[b,h] = x[b]·W[h] + bias[h] (B=131072, DIM=1024, NH=21)
//          result[b] = sum_h out[b,h]*vconf[b,h]
// d_out = [result (B) | out (B*NH)] fp32.
//
// Design (R2): lane owns one row, all 21 heads -> x reuse entirely in-thread,
// no cross-lane reduction. Per-WAVE async LDS staging (global_load_lds w16),
// double-buffered, NO __syncthreads anywhere (each wave reads only rows it
// staged itself). XOR swizzle for conflict-free b128 reads (row stride 32
// floats == bank period). W read with wave-uniform addresses -> scalar loads.

#define B_ROWS    131072
#define DIM       1024
#define NH        21
#define BK        32
#define NCHUNK    (DIM / BK)        // 32
#define NWAVES    2
#define BLOCK     (NWAVES * 64)     // 128 threads
#define TILE_ROWS (NWAVES * 64)     // 128 rows/block -> 1024 blocks
#define CG        (BK / 4)          // 8 float4 col-groups per chunk

__device__ __forceinline__ void gl_lds16(const float* g, float* l) {
    __builtin_amdgcn_global_load_lds(
        (const __attribute__((address_space(1))) void*)g,
        (__attribute__((address_space(3))) void*)l, 16, 0, 0);
}

__global__ __launch_bounds__(BLOCK) void linmodel_kernel(
    const float* __restrict__ x,      // [B, DIM]
    const float* __restrict__ vconf,  // [B, NH]
    const float* __restrict__ W,      // [NH, DIM]
    const float* __restrict__ bias,   // [NH]
    float* __restrict__ result,       // [B]
    float* __restrict__ out)          // [B, NH]
{
    // xs[buf][row][slot]: row stride 32 floats. Data (row r, colgroup c) lives
    // at slot c ^ (r&7). global_load_lds dest = base + 4*lane floats, which for
    // instr j covers row 8j+(lane>>3), slot lane&7 -- exactly matches.
    __shared__ float xs[2][TILE_ROWS * BK];

    const int tid  = threadIdx.x;
    const int wave = tid >> 6;
    const int lane = tid & 63;
    const int rloc = (wave << 6) + lane;                    // local row owned
    const long grow = (long)blockIdx.x * TILE_ROWS + rloc;  // global row owned

    // Staging coords for this lane (same for every instr j):
    const int pf_rowoff = lane >> 3;                         // row = 8j + this
    const int pf_cg     = (lane & 7) ^ (pf_rowoff & 7);      // source col-group
    // Global source row for instr j: blockBase + 64*wave + 8j + pf_rowoff
    const float* pf_src0 = x + ((long)blockIdx.x * TILE_ROWS + (wave << 6) + pf_rowoff) * DIM
                             + (pf_cg << 2);
    // LDS dest base (wave-uniform): wave region start
    const int lds_wave_base = (wave << 6) * BK;              // floats

#define PREFETCH(buf, c)                                                        \
    {                                                                           \
        const float* gs = pf_src0 + (c) * BK;                                   \
        float* ld = &xs[buf][lds_wave_base];                                    \
        _Pragma("unroll")                                                       \
        for (int j = 0; j < 8; ++j)                                             \
            gl_lds16(gs + (long)(8 * j) * DIM, ld + 256 * j);                   \
    }

    PREFETCH(0, 0)
    PREFETCH(1, 1)

    float acc[NH];
#pragma unroll
    for (int h = 0; h < NH; ++h) acc[h] = 0.f;

    const int swz = lane & 7;   // == rloc & 7

    for (int c = 0; c < NCHUNK; ++c) {
        const int buf = c & 1;
        // Oldest 8 outstanding (this chunk's) must be done; next chunk's 8 may fly.
        asm volatile("s_waitcnt vmcnt(8)" ::: "memory");

        float4 xv[CG];
#pragma unroll
        for (int cg = 0; cg < CG; ++cg)
            xv[cg] = *(const float4*)&xs[buf][rloc * BK + ((cg ^ swz) << 2)];

        // ds_reads retired -> safe to overwrite this buffer with chunk c+2.
        asm volatile("s_waitcnt lgkmcnt(0)" ::: "memory");
        if (c + 2 < NCHUNK) PREFETCH(buf, c + 2)

        // W addresses are wave-uniform (loop vars only) -> scalar loads.
        const float* Wc = W + c * BK;
#pragma unroll
        for (int h = 0; h < NH; ++h) {
            const float4* wr = (const float4*)(Wc + h * DIM);
#pragma unroll
            for (int cg = 0; cg < CG; ++cg) {
                const float4 w = wr[cg];
                acc[h] += xv[cg].x * w.x + xv[cg].y * w.y
                        + xv[cg].z * w.z + xv[cg].w * w.w;
            }
        }
    }

    // Epilogue: this lane fully owns its row.
    float r = 0.f;
    const float* vc = vconf + grow * NH;
    float* op = out + grow * NH;
#pragma unroll
    for (int h = 0; h < NH; ++h) {
        const float o = acc[h] + bias[h];   // bias: uniform -> scalar load
        op[h] = o;
        r += o * vc[h];
    }
    result[grow] = r;
#undef PREFETCH
}

extern "C" void kernel_launch(void* const* d_in, const int* in_sizes, int n_in,
                              void* d_out, int out_size, void* d_ws, size_t ws_size,
                              hipStream_t stream) {
    const float* x     = (const float*)d_in[0];
    const float* vconf = (const float*)d_in[1];
    const float* W     = (const float*)d_in[2];
    const float* bias  = (const float*)d_in[3];
    float* result = (float*)d_out;
    float* out    = (float*)d_out + B_ROWS;

    linmodel_kernel<<<dim3(B_ROWS / TILE_ROWS), dim3(BLOCK), 0, stream>>>(
        x, vconf, W, bias, result, out);
}